// Round 4
// baseline (248.824 us; speedup 1.0000x reference)
//
#include <hip/hip_runtime.h>
#include <hip/hip_bf16.h>

// Problem constants (from reference)
constexpr int BATCH = 4096;   // N
constexpr int NCLS  = 751;    // classes
constexpr int FDIM  = 2048;   // D
constexpr int TILE  = 128;    // C-tile (square)
constexpr int BK    = 32;     // K-step (one mfma_16x16x32 per step)
constexpr int NIT   = FDIM / BK;  // 64 K-iterations
constexpr float MARGIN = 0.5f;

constexpr int NTILE = BATCH / TILE;               // 32
constexpr int NOFF  = NTILE * (NTILE - 1) / 2;    // 496 strictly-lower tiles
constexpr int NWORK = NOFF + NTILE;               // 528 tiles total
constexpr int NWORKERS = 512;                     // 2 blocks/CU, dynamic queue

constexpr int NCONV = 512;                        // prep: convert blocks (8 rows each)
constexpr int NXENT = 512;                        // prep: xent blocks (8 rows each)

typedef __attribute__((ext_vector_type(8))) short bf16x8;  // 8 bf16 = 4 VGPRs
typedef __attribute__((ext_vector_type(4))) float f32x4;

// ---------------- helpers ----------------
__device__ __forceinline__ float wave_sum(float v) {
#pragma unroll
  for (int m = 32; m >= 1; m >>= 1) v += __shfl_xor(v, m, 64);
  return v;
}

__device__ __forceinline__ unsigned short bf_bits(float x) {
  unsigned u = __float_as_uint(x);
  u += 0x7FFFu + ((u >> 16) & 1u);   // RNE to bf16
  return (unsigned short)(u >> 16);
}

__device__ __forceinline__ void gld_lds16(const void* g, void* l) {
  __builtin_amdgcn_global_load_lds(
      (const __attribute__((address_space(1))) void*)g,
      (__attribute__((address_space(3))) void*)l, 16, 0, 0);
}

// ---------------- kernel 1 (prep): convert + xent + init, barrier-free -------
// blocks [0, NCONV): fp32->bf16 convert, 8 rows each (2 rows per wave).
// blocks [NCONV, NCONV+NXENT): cross-entropy, 8 rows each (2 rows per wave).
__global__ __launch_bounds__(256) void prep_kernel(
    const float* __restrict__ feat, const float* __restrict__ logits,
    const int* __restrict__ tgt, unsigned short* __restrict__ fb,
    float* __restrict__ sq, int* __restrict__ an, int* __restrict__ ap,
    float* __restrict__ xloss, int* __restrict__ ctrs) {
  const int b = blockIdx.x;
  const int tid = threadIdx.x;
  const int wave = tid >> 6, lane = tid & 63;

  if (b == 0 && tid == 0) { ctrs[0] = 0; ctrs[1] = 0; }  // ticket, done

  if (b < NCONV) {
    // -------- convert + row sum-of-squares + an/ap init --------
    if (tid < 8) {
      an[b * 8 + tid] = 0x7F000000;   // big positive float bits (min identity)
      ap[b * 8 + tid] = 0;            // 0.0f bits (max identity)
    }
#pragma unroll
    for (int rr = 0; rr < 2; ++rr) {
      const int row = b * 8 + wave * 2 + rr;
      const float4* src = (const float4*)(feat + (size_t)row * FDIM);
      ushort4* dst = (ushort4*)(fb + (size_t)row * FDIM);
      float s = 0.f;
#pragma unroll
      for (int it = 0; it < 8; ++it) {     // 512 float4 per row / 64 lanes
        const int idx = it * 64 + lane;
        float4 v = src[idx];
        s += v.x * v.x + v.y * v.y + v.z * v.z + v.w * v.w;
        ushort4 o;
        o.x = bf_bits(v.x); o.y = bf_bits(v.y);
        o.z = bf_bits(v.z); o.w = bf_bits(v.w);
        dst[idx] = o;
      }
      s = wave_sum(s);
      if (lane == 0) sq[row] = s;
    }
  } else {
    // -------- cross-entropy, one row per wave x2 --------
    const int r0 = (b - NCONV) * 8;
#pragma unroll
    for (int rr = 0; rr < 2; ++rr) {
      const int row = r0 + rr * 4 + wave;
      const float* lg = logits + (size_t)row * NCLS;
      float m = -1e30f;
      for (int j = lane; j < NCLS; j += 64) m = fmaxf(m, lg[j]);
#pragma unroll
      for (int s = 32; s >= 1; s >>= 1) m = fmaxf(m, __shfl_xor(m, s, 64));
      float se = 0.f;
      for (int j = lane; j < NCLS; j += 64) se += __expf(lg[j] - m);
      se = wave_sum(se);
      if (lane == 0) xloss[row] = -(lg[tgt[row]] - m - logf(se));
    }
  }
}

// ---------------- kernel 2 (mega): queued symmetric Gram + mining + final ----
// 512 worker blocks x 512 threads (8 waves). Each worker pulls tile indices
// from a global atomic ticket until the 528-tile queue drains. Tile: 128x128,
// wave grid 2x4 (wm rows of 64, wn cols of 32), each wave 4x2 MFMA sub-blocks.
// Double-buffered LDS; one global_load_lds dwordx4 per matrix per iter.
// The dynamically-last worker performs the final loss reduction.
__global__ __launch_bounds__(512, 4) void mega_kernel(
    const unsigned short* __restrict__ fb, const float* __restrict__ sq,
    int* __restrict__ an, int* __restrict__ ap,
    const float* __restrict__ xloss, float* __restrict__ out,
    int* __restrict__ ctrs) {
  __shared__ __align__(16) unsigned short As[2][TILE * BK];  // 2 x 8 KB
  __shared__ __align__(16) unsigned short Bs[2][TILE * BK];  // 2 x 8 KB
  __shared__ int s_tile;
  __shared__ int s_last;

  const int tid = threadIdx.x;
  const int wave = tid >> 6, lane = tid & 63;
  const int wm = wave >> 2, wn = wave & 3;        // 2x4 wave grid
  const int quad = lane >> 4, lr = lane & 15;
  // staging map: 512 threads x 16B = 8 KB = one full 128x32 tile per issue
  const int r = tid >> 2;          // 0..127
  const int c = (tid & 3) * 8;     // 0,8,16,24
  const int lo = r * BK + c;

  for (;;) {
    if (tid == 0) s_tile = atomicAdd(&ctrs[0], 1);
    __syncthreads();
    const int t = s_tile;
    if (t >= NWORK) break;

    int bi, bj;
    bool diag;
    if (t < NOFF) {   // strictly-lower triangle: t = bi*(bi-1)/2 + bj, bj < bi
      bi = (int)((1.f + sqrtf(8.f * (float)t + 1.f)) * 0.5f);
      while (bi * (bi - 1) / 2 > t) --bi;
      while ((bi + 1) * bi / 2 <= t) ++bi;
      bj = t - bi * (bi - 1) / 2;
      diag = false;
    } else {
      bi = bj = t - NOFF;
      diag = true;
    }
    const int i0 = bi * TILE, j0 = bj * TILE;

    f32x4 acc[4][2];
    const f32x4 zero = {0.f, 0.f, 0.f, 0.f};
#pragma unroll
    for (int mi = 0; mi < 4; ++mi)
#pragma unroll
      for (int ni = 0; ni < 2; ++ni) acc[mi][ni] = zero;

    const unsigned short* gA = fb + (size_t)(i0 + r) * FDIM + c;
    const unsigned short* gB = fb + (size_t)(j0 + r) * FDIM + c;

    // prefetch iteration 0 into buffer 0
    gld_lds16(gA, &As[0][lo]);
    if (!diag) gld_lds16(gB, &Bs[0][lo]);

    for (int it = 0; it < NIT; ++it) {
      const int cur = it & 1;
      __syncthreads();             // drains vmcnt -> buffer `cur` visible
      if (it + 1 < NIT) {
        const int nk = (it + 1) * BK;
        const int nb = cur ^ 1;
        gld_lds16(gA + nk, &As[nb][lo]);
        if (!diag) gld_lds16(gB + nk, &Bs[nb][lo]);
      }
      const unsigned short* Asb = As[cur];
      const unsigned short* Bsb = diag ? As[cur] : Bs[cur];

      bf16x8 a[4], bfr[2];
#pragma unroll
      for (int mi = 0; mi < 4; ++mi)
        a[mi] = *(const bf16x8*)&Asb[(wm * 64 + mi * 16 + lr) * BK + quad * 8];
#pragma unroll
      for (int ni = 0; ni < 2; ++ni)
        bfr[ni] = *(const bf16x8*)&Bsb[(wn * 32 + ni * 16 + lr) * BK + quad * 8];
#pragma unroll
      for (int mi = 0; mi < 4; ++mi)
#pragma unroll
        for (int ni = 0; ni < 2; ++ni)
          acc[mi][ni] = __builtin_amdgcn_mfma_f32_16x16x32_bf16(
              a[mi], bfr[ni], acc[mi][ni], 0, 0, 0);
    }

    // ---- epilogue: D layout col = lane&15 (j), row = quad*4 + reg (i) ----
    float sqj[2];
#pragma unroll
    for (int ni = 0; ni < 2; ++ni) sqj[ni] = sq[j0 + wn * 32 + ni * 16 + lr];

    if (diag) {
      float rmin[4][4], rmax[4][4];
#pragma unroll
      for (int mi = 0; mi < 4; ++mi)
#pragma unroll
        for (int rg = 0; rg < 4; ++rg) { rmin[mi][rg] = 1e30f; rmax[mi][rg] = 0.f; }
#pragma unroll
      for (int mi = 0; mi < 4; ++mi) {
#pragma unroll
        for (int rg = 0; rg < 4; ++rg) {
          const int i = i0 + wm * 64 + mi * 16 + quad * 4 + rg;
          const float si = sq[i];
          const int gi = i >> 2;       // targets = idx // 4
#pragma unroll
          for (int ni = 0; ni < 2; ++ni) {
            const int j = j0 + wn * 32 + ni * 16 + lr;
            const float d2 = si + sqj[ni] - 2.f * acc[mi][ni][rg];
            const float dist = sqrtf(fmaxf(d2, 1e-12f));
            if ((j >> 2) == gi) rmax[mi][rg] = fmaxf(rmax[mi][rg], dist);
            else                rmin[mi][rg] = fminf(rmin[mi][rg], dist);
          }
        }
      }
#pragma unroll
      for (int m = 1; m < 16; m <<= 1)
#pragma unroll
        for (int mi = 0; mi < 4; ++mi)
#pragma unroll
          for (int rg = 0; rg < 4; ++rg) {
            rmin[mi][rg] = fminf(rmin[mi][rg], __shfl_xor(rmin[mi][rg], m, 64));
            rmax[mi][rg] = fmaxf(rmax[mi][rg], __shfl_xor(rmax[mi][rg], m, 64));
          }
      if (lr == 0) {
#pragma unroll
        for (int mi = 0; mi < 4; ++mi)
#pragma unroll
          for (int rg = 0; rg < 4; ++rg) {
            const int i = i0 + wm * 64 + mi * 16 + quad * 4 + rg;
            atomicMin(&an[i], __float_as_int(rmin[mi][rg]));
            atomicMax(&ap[i], __float_as_int(rmax[mi][rg]));
          }
      }
    } else {
      float rmin[4][4];
      float cmin[2] = {1e30f, 1e30f};
#pragma unroll
      for (int mi = 0; mi < 4; ++mi)
#pragma unroll
        for (int rg = 0; rg < 4; ++rg) rmin[mi][rg] = 1e30f;
#pragma unroll
      for (int mi = 0; mi < 4; ++mi) {
#pragma unroll
        for (int rg = 0; rg < 4; ++rg) {
          const float si = sq[i0 + wm * 64 + mi * 16 + quad * 4 + rg];
#pragma unroll
          for (int ni = 0; ni < 2; ++ni) {
            const float d2 = si + sqj[ni] - 2.f * acc[mi][ni][rg];
            const float dist = sqrtf(fmaxf(d2, 1e-12f));
            rmin[mi][rg] = fminf(rmin[mi][rg], dist);
            cmin[ni] = fminf(cmin[ni], dist);
          }
        }
      }
      // rows: reduce across lr lanes (masks 1,2,4,8)
#pragma unroll
      for (int m = 1; m < 16; m <<= 1)
#pragma unroll
        for (int mi = 0; mi < 4; ++mi)
#pragma unroll
          for (int rg = 0; rg < 4; ++rg)
            rmin[mi][rg] = fminf(rmin[mi][rg], __shfl_xor(rmin[mi][rg], m, 64));
      if (lr == 0) {
#pragma unroll
        for (int mi = 0; mi < 4; ++mi)
#pragma unroll
          for (int rg = 0; rg < 4; ++rg) {
            const int i = i0 + wm * 64 + mi * 16 + quad * 4 + rg;
            atomicMin(&an[i], __float_as_int(rmin[mi][rg]));
          }
      }
      // cols: reduce across quad groups (masks 16,32); symmetry -> an[j]
#pragma unroll
      for (int ni = 0; ni < 2; ++ni) {
        cmin[ni] = fminf(cmin[ni], __shfl_xor(cmin[ni], 16, 64));
        cmin[ni] = fminf(cmin[ni], __shfl_xor(cmin[ni], 32, 64));
      }
      if (quad == 0) {
#pragma unroll
        for (int ni = 0; ni < 2; ++ni) {
          const int j = j0 + wn * 32 + ni * 16 + lr;
          atomicMin(&an[j], __float_as_int(cmin[ni]));
        }
      }
    }
  }

  // ---------------- done protocol + fused final reduction ----------------
  __threadfence();                 // publish this block's atomics (release)
  __syncthreads();
  if (tid == 0) s_last = (atomicAdd(&ctrs[1], 1) == NWORKERS - 1) ? 1 : 0;
  __syncthreads();
  if (s_last) {
    __threadfence();               // acquire
    float st = 0.f, sx = 0.f;
    for (int i = tid; i < BATCH; i += 512) {
      const float a = __int_as_float(__hip_atomic_load(
          &ap[i], __ATOMIC_RELAXED, __HIP_MEMORY_SCOPE_AGENT));
      const float b = __int_as_float(__hip_atomic_load(
          &an[i], __ATOMIC_RELAXED, __HIP_MEMORY_SCOPE_AGENT));
      st += fmaxf(a - b + MARGIN, 0.f);
      sx += xloss[i];
    }
    st = wave_sum(st);
    sx = wave_sum(sx);
    __shared__ float s1[8], s2[8];
    if (lane == 0) { s1[wave] = st; s2[wave] = sx; }
    __syncthreads();
    if (tid == 0) {
      float T = 0.f, X = 0.f;
#pragma unroll
      for (int w = 0; w < 8; ++w) { T += s1[w]; X += s2[w]; }
      out[0] = X / (float)BATCH + T / (float)BATCH;  // ALPHA=BETA=1
    }
  }
}

// ---------------- launch ----------------
extern "C" void kernel_launch(void* const* d_in, const int* in_sizes, int n_in,
                              void* d_out, int out_size, void* d_ws, size_t ws_size,
                              hipStream_t stream) {
  const float* logits = (const float*)d_in[0];
  const float* feat   = (const float*)d_in[1];
  const int*   tgt    = (const int*)d_in[2];
  float* out = (float*)d_out;

  // ws layout: bf16 feat copy (16 MB) | sq | an | ap | xloss | ctrs
  char* ws = (char*)d_ws;
  unsigned short* fb = (unsigned short*)ws;
  size_t off = (size_t)BATCH * FDIM * sizeof(unsigned short);
  float* sq    = (float*)(ws + off);  off += BATCH * sizeof(float);
  int*   an    = (int*)(ws + off);    off += BATCH * sizeof(int);
  int*   ap    = (int*)(ws + off);    off += BATCH * sizeof(int);
  float* xloss = (float*)(ws + off);  off += BATCH * sizeof(float);
  int*   ctrs  = (int*)(ws + off);

  prep_kernel<<<NCONV + NXENT, 256, 0, stream>>>(feat, logits, tgt, fb, sq, an,
                                                 ap, xloss, ctrs);
  mega_kernel<<<NWORKERS, 512, 0, stream>>>(fb, sq, an, ap, xloss, out, ctrs);
}